// Round 2
// baseline (1472.101 us; speedup 1.0000x reference)
//
#include <hip/hip_runtime.h>
#include <hip/hip_bf16.h>
#include <cstdint>

typedef unsigned short u16;
typedef unsigned int u32;
typedef short s16x8 __attribute__((ext_vector_type(8)));
typedef float f32x4 __attribute__((ext_vector_type(4)));

// Problem constants (B=4, T=2048, D=1024, E=8, H=2048, K=2)
constexpr int NTOK = 8192;
constexpr int DDIM = 1024;
constexpr int NEXP = 8;
constexpr int HDIM = 2048;
constexpr int NPAIR = NTOK * 2;   // 16384

// d_out layout (floats), concatenated tuple
constexpr size_t OFF_OUT   = 0;
constexpr size_t OFF_AUX   = 8388608;
constexpr size_t OFF_PROBS = 8388609;
constexpr size_t OFF_TIDX  = 8454145;
constexpr size_t OFF_TPR   = 8470529;

// workspace layout (bytes)
constexpr size_t WS_CNT  = 0;          // 8 int
constexpr size_t WS_PSUM = 32;         // 8 float
constexpr size_t WS_BASE = 64;         // 8 int
constexpr size_t WS_IDS  = 1024;       // 8*8192 int
constexpr size_t WS_EPOS = 263168;     // 16384 int
constexpr size_t WS_XB   = 393216;     // 8192*1024 bf16
constexpr size_t WS_W1T  = 17170432;   // 8*2048*1024 bf16 (transposed [E][H][D])
constexpr size_t WS_W2T  = 50724864;   // 8*1024*2048 bf16 (transposed [E][D][H])
constexpr size_t WS_H    = 84279296;   // 16384*2048 bf16
constexpr size_t WS_Y    = 151388160;  // 16384*1024 f32
constexpr size_t WS_NEED = 218497024;

__device__ __forceinline__ u16 f2b(float f) {
  u32 u = __float_as_uint(f);
  u32 r = (u + 0x7fffu + ((u >> 16) & 1u)) >> 16;
  return (u16)r;
}
__device__ __forceinline__ float b2f(u16 h) {
  return __uint_as_float(((u32)h) << 16);
}

typedef const uint32_t __attribute__((address_space(1)))* gptr_t;
typedef uint32_t __attribute__((address_space(3)))* lptr_t;

__device__ __forceinline__ void gload16(const void* gp, void* lp) {
  __builtin_amdgcn_global_load_lds((gptr_t)gp, (lptr_t)(uintptr_t)lp, 16, 0, 0);
}

// ---------------- f32 -> bf16 convert (vectorized) ----------------
__global__ __launch_bounds__(256) void cvt_kernel(const float* __restrict__ in,
                                                  u16* __restrict__ out, int n4) {
  int i = blockIdx.x * blockDim.x + threadIdx.x;
  int stride = gridDim.x * blockDim.x;
  for (; i < n4; i += stride) {
    float4 v = ((const float4*)in)[i];
    ushort4 o;
    o.x = f2b(v.x); o.y = f2b(v.y); o.z = f2b(v.z); o.w = f2b(v.w);
    ((ushort4*)out)[i] = o;
  }
}

// ------------- transpose + convert: in [E][R][C] f32 -> out [E][C][R] bf16 -------------
__global__ __launch_bounds__(256) void tconv_kernel(const float* __restrict__ in,
                                                    u16* __restrict__ out, int R, int C) {
  __shared__ float tile[64][65];
  int e = blockIdx.z;
  int c0 = blockIdx.x * 64, r0 = blockIdx.y * 64;
  int tx = threadIdx.x & 15, ty = threadIdx.x >> 4;
  const float* src = in + (size_t)e * R * C;
#pragma unroll
  for (int i = 0; i < 4; ++i) {
    int r = ty + i * 16;
    float4 v = *(const float4*)(src + (size_t)(r0 + r) * C + c0 + tx * 4);
    tile[r][tx * 4 + 0] = v.x; tile[r][tx * 4 + 1] = v.y;
    tile[r][tx * 4 + 2] = v.z; tile[r][tx * 4 + 3] = v.w;
  }
  __syncthreads();
  u16* dst = out + (size_t)e * R * C;
#pragma unroll
  for (int i = 0; i < 4; ++i) {
    int c = ty + i * 16;
    ushort4 o;
    o.x = f2b(tile[tx * 4 + 0][c]); o.y = f2b(tile[tx * 4 + 1][c]);
    o.z = f2b(tile[tx * 4 + 2][c]); o.w = f2b(tile[tx * 4 + 3][c]);
    *(ushort4*)(dst + (size_t)(c0 + c) * R + r0 + tx * 4) = o;
  }
}

// ---------------- router: logits, softmax, top-2, routing lists ----------------
__global__ __launch_bounds__(256) void router_kernel(
    const float* __restrict__ x, const float* __restrict__ gw,
    float* __restrict__ outbuf, int* __restrict__ cnt, float* __restrict__ psum,
    int* __restrict__ ids, int* __restrict__ epos) {
  const int t = blockIdx.x;
  const int tid = threadIdx.x;
  const float4 xv = ((const float4*)(x + (size_t)t * DDIM))[tid];
  double acc[NEXP];
#pragma unroll
  for (int e = 0; e < NEXP; ++e) acc[e] = 0.0;
  const float* g = gw + (size_t)tid * 4 * NEXP;
#pragma unroll
  for (int i = 0; i < 4; ++i) {
    double xs = (double)((const float*)&xv)[i];
#pragma unroll
    for (int e = 0; e < NEXP; ++e) acc[e] += xs * (double)g[i * NEXP + e];
  }
#pragma unroll
  for (int e = 0; e < NEXP; ++e)
    for (int off = 32; off > 0; off >>= 1) acc[e] += __shfl_down(acc[e], off);
  __shared__ double red[4][NEXP];
  int lane = tid & 63, wv = tid >> 6;
  if (lane == 0)
    for (int e = 0; e < NEXP; ++e) red[wv][e] = acc[e];
  __syncthreads();
  if (tid == 0) {
    float l[NEXP];
#pragma unroll
    for (int e = 0; e < NEXP; ++e)
      l[e] = (float)(red[0][e] + red[1][e] + red[2][e] + red[3][e]);
    float m = l[0];
#pragma unroll
    for (int e = 1; e < NEXP; ++e) m = fmaxf(m, l[e]);
    float p[NEXP], s = 0.f;
#pragma unroll
    for (int e = 0; e < NEXP; ++e) { p[e] = expf(l[e] - m); s += p[e]; }
    float inv = 1.0f / s;
#pragma unroll
    for (int e = 0; e < NEXP; ++e) {
      p[e] *= inv;
      outbuf[OFF_PROBS + (size_t)t * NEXP + e] = p[e];
    }
    int e0 = 0;
#pragma unroll
    for (int e = 1; e < NEXP; ++e) if (p[e] > p[e0]) e0 = e;
    int e1 = -1;
#pragma unroll
    for (int e = 0; e < NEXP; ++e)
      if (e != e0 && (e1 < 0 || p[e] > p[e1])) e1 = e;
    float ps = p[e0] + p[e1];
    outbuf[OFF_TIDX + t * 2 + 0] = (float)e0;
    outbuf[OFF_TIDX + t * 2 + 1] = (float)e1;
    outbuf[OFF_TPR + t * 2 + 0] = p[e0] / ps;
    outbuf[OFF_TPR + t * 2 + 1] = p[e1] / ps;
    int pos0 = atomicAdd(&cnt[e0], 1);
    ids[e0 * NTOK + pos0] = t;
    epos[t * 2 + 0] = (e0 << 16) | pos0;
    int pos1 = atomicAdd(&cnt[e1], 1);
    ids[e1 * NTOK + pos1] = t;
    epos[t * 2 + 1] = (e1 << 16) | pos1;
#pragma unroll
    for (int e = 0; e < NEXP; ++e) atomicAdd(&psum[e], p[e]);
  }
}

// ---------------- bases + aux loss ----------------
__global__ void finalize_kernel(const int* __restrict__ cnt,
                                const float* __restrict__ psum,
                                int* __restrict__ base, float* __restrict__ outbuf) {
  if (threadIdx.x == 0 && blockIdx.x == 0) {
    int b = 0;
    float aux = 0.f;
    for (int e = 0; e < NEXP; ++e) {
      base[e] = b;
      b += cnt[e];
      aux += (float)cnt[e] * psum[e];
    }
    outbuf[OFF_AUX] = aux * (float)NEXP / ((float)NTOK * (float)NTOK);
  }
}

// ---------------- grouped GEMM ----------------
// MODE 0: A = x_bf16 gathered rows [*,1024], B = w1t [E][2048][1024], C = h (bf16, gelu)
// MODE 1: A = h contiguous rows   [*,2048], B = w2t [E][1024][2048], C = y (f32)
template <int MODE>
__global__ __launch_bounds__(256) void moe_gemm_kernel(
    const u16* __restrict__ Asrc, const u16* __restrict__ Bt,
    u16* __restrict__ hout, float* __restrict__ yout,
    const int* __restrict__ cnt, const int* __restrict__ base,
    const int* __restrict__ ids) {
  constexpr int KDIM = (MODE == 0) ? 1024 : 2048;
  constexpr int NDIM = (MODE == 0) ? 2048 : 1024;
  const int e = blockIdx.z;
  const int cnte = cnt[e];
  const int m0 = blockIdx.x * 128;
  if (m0 >= cnte) return;
  const int n0 = blockIdx.y * 128;
  const int gbase = base[e];

  __shared__ u16 Al[128 * 64];
  __shared__ u16 Bl[128 * 64];

  const int tid = threadIdx.x;
  const int lane = tid & 63, wid = tid >> 6;
  const int wm = (wid >> 1) * 64, wn = (wid & 1) * 64;
  const int r15 = lane & 15, l4 = lane >> 4;

  // staging precompute: per q, LDS slot j=q*256+tid -> row=j>>3, chunk cp=j&7,
  // holds global chunk c = cp ^ (row&7)  (both-sides XOR swizzle)
  const char* aptr[4];
  const char* bptr[4];
#pragma unroll
  for (int q = 0; q < 4; ++q) {
    int j = q * 256 + tid;
    int row = j >> 3;
    int c = (j & 7) ^ (row & 7);
    size_t rowoff;
    if (MODE == 0) {
      int mm = m0 + row;
      int tok = (mm < cnte) ? ids[e * NTOK + mm] : 0;
      rowoff = (size_t)tok * KDIM;
    } else {
      int gr = gbase + m0 + row;
      if (gr > NPAIR - 1) gr = NPAIR - 1;
      rowoff = (size_t)gr * KDIM;
    }
    aptr[q] = (const char*)Asrc + (rowoff + (size_t)c * 8) * 2;
    size_t nrow = (size_t)e * NDIM + n0 + row;
    bptr[q] = (const char*)Bt + (nrow * KDIM + (size_t)c * 8) * 2;
  }

  f32x4 acc[4][4];
#pragma unroll
  for (int i = 0; i < 4; ++i)
#pragma unroll
    for (int jn = 0; jn < 4; ++jn) acc[i][jn] = (f32x4){0.f, 0.f, 0.f, 0.f};

  const s16x8* Av = (const s16x8*)Al;
  const s16x8* Bv = (const s16x8*)Bl;

  for (int kt = 0; kt < KDIM / 64; ++kt) {
    const size_t kofs = (size_t)kt * 128;  // bytes: 64 bf16
#pragma unroll
    for (int q = 0; q < 4; ++q)
      gload16(aptr[q] + kofs, (void*)&Al[(size_t)(q * 256 + tid) * 8]);
#pragma unroll
    for (int q = 0; q < 4; ++q)
      gload16(bptr[q] + kofs, (void*)&Bl[(size_t)(q * 256 + tid) * 8]);
    asm volatile("s_waitcnt vmcnt(0)" ::: "memory");
    __syncthreads();

#pragma unroll
    for (int kh = 0; kh < 2; ++kh) {
      s16x8 af[4], bfr[4];
#pragma unroll
      for (int mi = 0; mi < 4; ++mi) {
        int row = wm + mi * 16 + r15;
        af[mi] = Av[row * 8 + ((kh * 4 + l4) ^ (row & 7))];
      }
#pragma unroll
      for (int ni = 0; ni < 4; ++ni) {
        int row = wn + ni * 16 + r15;
        bfr[ni] = Bv[row * 8 + ((kh * 4 + l4) ^ (row & 7))];
      }
#pragma unroll
      for (int mi = 0; mi < 4; ++mi)
#pragma unroll
        for (int ni = 0; ni < 4; ++ni)
          acc[mi][ni] = __builtin_amdgcn_mfma_f32_16x16x32_bf16(
              af[mi], bfr[ni], acc[mi][ni], 0, 0, 0);
    }
    __syncthreads();
  }

  // epilogue: C/D layout col = lane&15, row = (lane>>4)*4 + j
#pragma unroll
  for (int mi = 0; mi < 4; ++mi) {
#pragma unroll
    for (int jr = 0; jr < 4; ++jr) {
      int rl = wm + mi * 16 + l4 * 4 + jr;
      if (m0 + rl < cnte) {
        size_t grow = (size_t)(gbase + m0 + rl);
#pragma unroll
        for (int ni = 0; ni < 4; ++ni) {
          float v = acc[mi][ni][jr];
          int col = n0 + wn + ni * 16 + r15;
          if (MODE == 0) {
            v = 0.5f * v * (1.0f + erff(v * 0.70710678118654752f));
            hout[grow * NDIM + col] = f2b(v);
          } else {
            yout[grow * NDIM + col] = v;
          }
        }
      }
    }
  }
}

// ---------------- combine: out[t] = p0*y[r0] + p1*y[r1] ----------------
__global__ __launch_bounds__(256) void combine_kernel(
    const float* __restrict__ y, float* __restrict__ outbuf,
    const int* __restrict__ epos, const int* __restrict__ base) {
  int t = blockIdx.x;
  int ep0 = epos[t * 2], ep1 = epos[t * 2 + 1];
  size_t r0 = (size_t)base[ep0 >> 16] + (ep0 & 0xffff);
  size_t r1 = (size_t)base[ep1 >> 16] + (ep1 & 0xffff);
  float p0 = outbuf[OFF_TPR + t * 2], p1 = outbuf[OFF_TPR + t * 2 + 1];
  int d0 = threadIdx.x * 4;
  float4 a = *(const float4*)(y + r0 * DDIM + d0);
  float4 b = *(const float4*)(y + r1 * DDIM + d0);
  float4 o;
  o.x = p0 * a.x + p1 * b.x;
  o.y = p0 * a.y + p1 * b.y;
  o.z = p0 * a.z + p1 * b.z;
  o.w = p0 * a.w + p1 * b.w;
  *(float4*)(outbuf + OFF_OUT + (size_t)t * DDIM + d0) = o;
}

extern "C" void kernel_launch(void* const* d_in, const int* in_sizes, int n_in,
                              void* d_out, int out_size, void* d_ws, size_t ws_size,
                              hipStream_t stream) {
  const float* x = (const float*)d_in[0];
  const float* gw = (const float*)d_in[1];
  const float* w1 = (const float*)d_in[2];
  const float* w2 = (const float*)d_in[3];
  float* out = (float*)d_out;
  char* w = (char*)d_ws;
  if (ws_size < WS_NEED) return;  // insufficient workspace -> loud failure

  int* cnt = (int*)(w + WS_CNT);
  float* psum = (float*)(w + WS_PSUM);
  int* base = (int*)(w + WS_BASE);
  int* ids = (int*)(w + WS_IDS);
  int* epos = (int*)(w + WS_EPOS);
  u16* xb = (u16*)(w + WS_XB);
  u16* w1t = (u16*)(w + WS_W1T);
  u16* w2t = (u16*)(w + WS_W2T);
  u16* hbuf = (u16*)(w + WS_H);
  float* ybuf = (float*)(w + WS_Y);

  (void)hipMemsetAsync(w, 0, 64, stream);
  cvt_kernel<<<2048, 256, 0, stream>>>(x, xb, NTOK * DDIM / 4);
  // w1 [E][1024][2048] -> w1t [E][2048][1024]
  tconv_kernel<<<dim3(HDIM / 64, DDIM / 64, NEXP), 256, 0, stream>>>(w1, w1t, DDIM, HDIM);
  // w2 [E][2048][1024] -> w2t [E][1024][2048]
  tconv_kernel<<<dim3(DDIM / 64, HDIM / 64, NEXP), 256, 0, stream>>>(w2, w2t, HDIM, DDIM);
  router_kernel<<<NTOK, 256, 0, stream>>>(x, gw, out, cnt, psum, ids, epos);
  finalize_kernel<<<1, 64, 0, stream>>>(cnt, psum, base, out);
  moe_gemm_kernel<0><<<dim3(64, HDIM / 128, NEXP), 256, 0, stream>>>(
      xb, w1t, hbuf, nullptr, cnt, base, ids);
  moe_gemm_kernel<1><<<dim3(64, DDIM / 128, NEXP), 256, 0, stream>>>(
      hbuf, w2t, nullptr, ybuf, cnt, base, ids);
  combine_kernel<<<NTOK, 256, 0, stream>>>(ybuf, out, epos, base);
}

// Round 3
// 473.372 us; speedup vs baseline: 3.1098x; 3.1098x over previous
//
#include <hip/hip_runtime.h>
#include <hip/hip_bf16.h>
#include <cstdint>

typedef unsigned short u16;
typedef unsigned int u32;
typedef short s16x8 __attribute__((ext_vector_type(8)));
typedef float f32x4 __attribute__((ext_vector_type(4)));

// Problem constants (B=4, T=2048, D=1024, E=8, H=2048, K=2)
constexpr int NTOK = 8192;
constexpr int DDIM = 1024;
constexpr int NEXP = 8;
constexpr int HDIM = 2048;
constexpr int NPAIR = NTOK * 2;   // 16384

// d_out layout (floats), concatenated tuple
constexpr size_t OFF_OUT   = 0;
constexpr size_t OFF_AUX   = 8388608;
constexpr size_t OFF_PROBS = 8388609;
constexpr size_t OFF_TIDX  = 8454145;
constexpr size_t OFF_TPR   = 8470529;

// workspace layout (bytes)
constexpr size_t WS_CNT  = 0;          // 8 int
constexpr size_t WS_PSUM = 32;         // 8 float
constexpr size_t WS_BASE = 64;         // 8 int
constexpr size_t WS_IDS  = 1024;       // 8*8192 int
constexpr size_t WS_EPOS = 263168;     // 16384 int
constexpr size_t WS_XB   = 393216;     // 8192*1024 bf16
constexpr size_t WS_W1T  = 17170432;   // 8*2048*1024 bf16 (transposed [E][H][D])
constexpr size_t WS_W2T  = 50724864;   // 8*1024*2048 bf16 (transposed [E][D][H])
constexpr size_t WS_H    = 84279296;   // 16384*2048 bf16
constexpr size_t WS_Y    = 151388160;  // 16384*1024 f32
constexpr size_t WS_NEED = 218497024;

__device__ __forceinline__ u16 f2b(float f) {
  u32 u = __float_as_uint(f);
  u32 r = (u + 0x7fffu + ((u >> 16) & 1u)) >> 16;
  return (u16)r;
}

typedef const uint32_t __attribute__((address_space(1)))* gptr_t;
typedef uint32_t __attribute__((address_space(3)))* lptr_t;

__device__ __forceinline__ void gload16(const void* gp, void* lp) {
  __builtin_amdgcn_global_load_lds((gptr_t)gp, (lptr_t)(uintptr_t)lp, 16, 0, 0);
}

// ------------- transpose + convert: in [E][R][C] f32 -> out [E][C][R] bf16 -------------
__global__ __launch_bounds__(256) void tconv_kernel(const float* __restrict__ in,
                                                    u16* __restrict__ out, int R, int C) {
  __shared__ float tile[64][65];
  int e = blockIdx.z;
  int c0 = blockIdx.x * 64, r0 = blockIdx.y * 64;
  int tx = threadIdx.x & 15, ty = threadIdx.x >> 4;
  const float* src = in + (size_t)e * R * C;
#pragma unroll
  for (int i = 0; i < 4; ++i) {
    int r = ty + i * 16;
    float4 v = *(const float4*)(src + (size_t)(r0 + r) * C + c0 + tx * 4);
    tile[r][tx * 4 + 0] = v.x; tile[r][tx * 4 + 1] = v.y;
    tile[r][tx * 4 + 2] = v.z; tile[r][tx * 4 + 3] = v.w;
  }
  __syncthreads();
  u16* dst = out + (size_t)e * R * C;
#pragma unroll
  for (int i = 0; i < 4; ++i) {
    int c = ty + i * 16;
    ushort4 o;
    o.x = f2b(tile[tx * 4 + 0][c]); o.y = f2b(tile[tx * 4 + 1][c]);
    o.z = f2b(tile[tx * 4 + 2][c]); o.w = f2b(tile[tx * 4 + 3][c]);
    *(ushort4*)(dst + (size_t)(c0 + c) * R + r0 + tx * 4) = o;
  }
}

// ---------------- router: 64 tokens/block; fused x->bf16; block-local counting ----------------
__global__ __launch_bounds__(256) void router_kernel(
    const float* __restrict__ x, const float* __restrict__ gw,
    u16* __restrict__ xb, float* __restrict__ outbuf,
    int* __restrict__ cnt, float* __restrict__ psum,
    int* __restrict__ ids, int* __restrict__ epos) {
  __shared__ float gwl[DDIM * NEXP];  // 32 KB
  __shared__ int lcnt[NEXP];
  __shared__ float psl[NEXP];
  __shared__ int gbl[NEXP];

  const int tid = threadIdx.x;
#pragma unroll
  for (int k = 0; k < 8; ++k)
    ((float4*)gwl)[tid + k * 256] = ((const float4*)gw)[tid + k * 256];
  if (tid < NEXP) { lcnt[tid] = 0; psl[tid] = 0.f; }
  __syncthreads();

  const int tloc = tid >> 2, part = tid & 3;
  const int t = blockIdx.x * 64 + tloc;
  double acc[NEXP];
#pragma unroll
  for (int e = 0; e < NEXP; ++e) acc[e] = 0.0;

  const float* xrow = x + (size_t)t * DDIM + part * 256;
  u16* xbrow = xb + (size_t)t * DDIM + part * 256;
  for (int i = 0; i < 64; ++i) {
    float4 v = ((const float4*)xrow)[i];
    ushort4 o;
    o.x = f2b(v.x); o.y = f2b(v.y); o.z = f2b(v.z); o.w = f2b(v.w);
    ((ushort4*)xbrow)[i] = o;
    const float* g = &gwl[(part * 256 + i * 4) * NEXP];
#pragma unroll
    for (int j = 0; j < 4; ++j) {
      double xs = (double)((const float*)&v)[j];
#pragma unroll
      for (int e = 0; e < NEXP; ++e) acc[e] += xs * (double)g[j * NEXP + e];
    }
  }
  // parts of one token sit on 4 consecutive lanes -> butterfly reduce
#pragma unroll
  for (int e = 0; e < NEXP; ++e) {
    acc[e] += __shfl_xor(acc[e], 1);
    acc[e] += __shfl_xor(acc[e], 2);
  }

  int e0 = 0, e1 = 0, lp0 = 0, lp1 = 0;
  if (part == 0) {
    float l[NEXP];
#pragma unroll
    for (int e = 0; e < NEXP; ++e) l[e] = (float)acc[e];
    float m = l[0];
#pragma unroll
    for (int e = 1; e < NEXP; ++e) m = fmaxf(m, l[e]);
    float p[NEXP], s = 0.f;
#pragma unroll
    for (int e = 0; e < NEXP; ++e) { p[e] = expf(l[e] - m); s += p[e]; }
    float inv = 1.0f / s;
#pragma unroll
    for (int e = 0; e < NEXP; ++e) {
      p[e] *= inv;
      outbuf[OFF_PROBS + (size_t)t * NEXP + e] = p[e];
      atomicAdd(&psl[e], p[e]);
    }
#pragma unroll
    for (int e = 1; e < NEXP; ++e) if (p[e] > p[e0]) e0 = e;
    e1 = -1;
#pragma unroll
    for (int e = 0; e < NEXP; ++e)
      if (e != e0 && (e1 < 0 || p[e] > p[e1])) e1 = e;
    float ps = p[e0] + p[e1];
    outbuf[OFF_TIDX + t * 2 + 0] = (float)e0;
    outbuf[OFF_TIDX + t * 2 + 1] = (float)e1;
    outbuf[OFF_TPR + t * 2 + 0] = p[e0] / ps;
    outbuf[OFF_TPR + t * 2 + 1] = p[e1] / ps;
    lp0 = atomicAdd(&lcnt[e0], 1);
    lp1 = atomicAdd(&lcnt[e1], 1);
  }
  __syncthreads();
  if (tid < NEXP) {
    gbl[tid] = atomicAdd(&cnt[tid], lcnt[tid]);
    atomicAdd(&psum[tid], psl[tid]);
  }
  __syncthreads();
  if (part == 0) {
    int pos0 = gbl[e0] + lp0;
    int pos1 = gbl[e1] + lp1;
    ids[e0 * NTOK + pos0] = t;
    ids[e1 * NTOK + pos1] = t;
    epos[t * 2 + 0] = (e0 << 16) | pos0;
    epos[t * 2 + 1] = (e1 << 16) | pos1;
  }
}

// ---------------- bases + aux loss ----------------
__global__ void finalize_kernel(const int* __restrict__ cnt,
                                const float* __restrict__ psum,
                                int* __restrict__ base, float* __restrict__ outbuf) {
  if (threadIdx.x == 0 && blockIdx.x == 0) {
    int b = 0;
    float aux = 0.f;
    for (int e = 0; e < NEXP; ++e) {
      base[e] = b;
      b += cnt[e];
      aux += (float)cnt[e] * psum[e];
    }
    outbuf[OFF_AUX] = aux * (float)NEXP / ((float)NTOK * (float)NTOK);
  }
}

// ---------------- grouped GEMM ----------------
// MODE 0: A = x_bf16 gathered rows [*,1024], B = w1t [E][2048][1024], C = h (bf16, gelu)
// MODE 1: A = h contiguous rows   [*,2048], B = w2t [E][1024][2048], C = y (f32)
template <int MODE>
__global__ __launch_bounds__(256) void moe_gemm_kernel(
    const u16* __restrict__ Asrc, const u16* __restrict__ Bt,
    u16* __restrict__ hout, float* __restrict__ yout,
    const int* __restrict__ cnt, const int* __restrict__ base,
    const int* __restrict__ ids) {
  constexpr int KDIM = (MODE == 0) ? 1024 : 2048;
  constexpr int NDIM = (MODE == 0) ? 2048 : 1024;
  const int e = blockIdx.z;
  const int cnte = cnt[e];
  const int m0 = blockIdx.x * 128;
  if (m0 >= cnte) return;
  const int n0 = blockIdx.y * 128;
  const int gbase = base[e];

  __shared__ u16 Al[128 * 64];
  __shared__ u16 Bl[128 * 64];

  const int tid = threadIdx.x;
  const int lane = tid & 63, wid = tid >> 6;
  const int wm = (wid >> 1) * 64, wn = (wid & 1) * 64;
  const int r15 = lane & 15, l4 = lane >> 4;

  // staging precompute: per q, LDS slot j=q*256+tid -> row=j>>3, chunk cp=j&7,
  // holds global chunk c = cp ^ (row&7)  (both-sides XOR swizzle)
  const char* aptr[4];
  const char* bptr[4];
#pragma unroll
  for (int q = 0; q < 4; ++q) {
    int j = q * 256 + tid;
    int row = j >> 3;
    int c = (j & 7) ^ (row & 7);
    size_t rowoff;
    if (MODE == 0) {
      int mm = m0 + row;
      int tok = (mm < cnte) ? ids[e * NTOK + mm] : 0;
      rowoff = (size_t)tok * KDIM;
    } else {
      int gr = gbase + m0 + row;
      if (gr > NPAIR - 1) gr = NPAIR - 1;
      rowoff = (size_t)gr * KDIM;
    }
    aptr[q] = (const char*)Asrc + (rowoff + (size_t)c * 8) * 2;
    size_t nrow = (size_t)e * NDIM + n0 + row;
    bptr[q] = (const char*)Bt + (nrow * KDIM + (size_t)c * 8) * 2;
  }

  f32x4 acc[4][4];
#pragma unroll
  for (int i = 0; i < 4; ++i)
#pragma unroll
    for (int jn = 0; jn < 4; ++jn) acc[i][jn] = (f32x4){0.f, 0.f, 0.f, 0.f};

  const s16x8* Av = (const s16x8*)Al;
  const s16x8* Bv = (const s16x8*)Bl;

  for (int kt = 0; kt < KDIM / 64; ++kt) {
    const size_t kofs = (size_t)kt * 128;  // bytes: 64 bf16
#pragma unroll
    for (int q = 0; q < 4; ++q)
      gload16(aptr[q] + kofs, (void*)&Al[(size_t)(q * 256 + tid) * 8]);
#pragma unroll
    for (int q = 0; q < 4; ++q)
      gload16(bptr[q] + kofs, (void*)&Bl[(size_t)(q * 256 + tid) * 8]);
    asm volatile("s_waitcnt vmcnt(0)" ::: "memory");
    __syncthreads();

#pragma unroll
    for (int kh = 0; kh < 2; ++kh) {
      s16x8 af[4], bfr[4];
#pragma unroll
      for (int mi = 0; mi < 4; ++mi) {
        int row = wm + mi * 16 + r15;
        af[mi] = Av[row * 8 + ((kh * 4 + l4) ^ (row & 7))];
      }
#pragma unroll
      for (int ni = 0; ni < 4; ++ni) {
        int row = wn + ni * 16 + r15;
        bfr[ni] = Bv[row * 8 + ((kh * 4 + l4) ^ (row & 7))];
      }
#pragma unroll
      for (int mi = 0; mi < 4; ++mi)
#pragma unroll
        for (int ni = 0; ni < 4; ++ni)
          acc[mi][ni] = __builtin_amdgcn_mfma_f32_16x16x32_bf16(
              af[mi], bfr[ni], acc[mi][ni], 0, 0, 0);
    }
    __syncthreads();
  }

  // epilogue: C/D layout col = lane&15, row = (lane>>4)*4 + j
#pragma unroll
  for (int mi = 0; mi < 4; ++mi) {
#pragma unroll
    for (int jr = 0; jr < 4; ++jr) {
      int rl = wm + mi * 16 + l4 * 4 + jr;
      if (m0 + rl < cnte) {
        size_t grow = (size_t)(gbase + m0 + rl);
#pragma unroll
        for (int ni = 0; ni < 4; ++ni) {
          float v = acc[mi][ni][jr];
          int col = n0 + wn + ni * 16 + r15;
          if (MODE == 0) {
            v = 0.5f * v * (1.0f + erff(v * 0.70710678118654752f));
            hout[grow * NDIM + col] = f2b(v);
          } else {
            yout[grow * NDIM + col] = v;
          }
        }
      }
    }
  }
}

// ---------------- combine: out[t] = p0*y[r0] + p1*y[r1] ----------------
__global__ __launch_bounds__(256) void combine_kernel(
    const float* __restrict__ y, float* __restrict__ outbuf,
    const int* __restrict__ epos, const int* __restrict__ base) {
  int t = blockIdx.x;
  int ep0 = epos[t * 2], ep1 = epos[t * 2 + 1];
  size_t r0 = (size_t)base[ep0 >> 16] + (ep0 & 0xffff);
  size_t r1 = (size_t)base[ep1 >> 16] + (ep1 & 0xffff);
  float p0 = outbuf[OFF_TPR + t * 2], p1 = outbuf[OFF_TPR + t * 2 + 1];
  int d0 = threadIdx.x * 4;
  float4 a = *(const float4*)(y + r0 * DDIM + d0);
  float4 b = *(const float4*)(y + r1 * DDIM + d0);
  float4 o;
  o.x = p0 * a.x + p1 * b.x;
  o.y = p0 * a.y + p1 * b.y;
  o.z = p0 * a.z + p1 * b.z;
  o.w = p0 * a.w + p1 * b.w;
  *(float4*)(outbuf + OFF_OUT + (size_t)t * DDIM + d0) = o;
}

extern "C" void kernel_launch(void* const* d_in, const int* in_sizes, int n_in,
                              void* d_out, int out_size, void* d_ws, size_t ws_size,
                              hipStream_t stream) {
  const float* x = (const float*)d_in[0];
  const float* gw = (const float*)d_in[1];
  const float* w1 = (const float*)d_in[2];
  const float* w2 = (const float*)d_in[3];
  float* out = (float*)d_out;
  char* w = (char*)d_ws;
  if (ws_size < WS_NEED) return;  // insufficient workspace -> loud failure

  int* cnt = (int*)(w + WS_CNT);
  float* psum = (float*)(w + WS_PSUM);
  int* base = (int*)(w + WS_BASE);
  int* ids = (int*)(w + WS_IDS);
  int* epos = (int*)(w + WS_EPOS);
  u16* xb = (u16*)(w + WS_XB);
  u16* w1t = (u16*)(w + WS_W1T);
  u16* w2t = (u16*)(w + WS_W2T);
  u16* hbuf = (u16*)(w + WS_H);
  float* ybuf = (float*)(w + WS_Y);

  (void)hipMemsetAsync(w, 0, 64, stream);
  // router also emits xb (x converted to bf16)
  router_kernel<<<NTOK / 64, 256, 0, stream>>>(x, gw, xb, out, cnt, psum, ids, epos);
  // w1 [E][1024][2048] -> w1t [E][2048][1024]
  tconv_kernel<<<dim3(HDIM / 64, DDIM / 64, NEXP), 256, 0, stream>>>(w1, w1t, DDIM, HDIM);
  // w2 [E][2048][1024] -> w2t [E][1024][2048]
  tconv_kernel<<<dim3(DDIM / 64, HDIM / 64, NEXP), 256, 0, stream>>>(w2, w2t, HDIM, DDIM);
  finalize_kernel<<<1, 64, 0, stream>>>(cnt, psum, base, out);
  moe_gemm_kernel<0><<<dim3(64, HDIM / 128, NEXP), 256, 0, stream>>>(
      xb, w1t, hbuf, nullptr, cnt, base, ids);
  moe_gemm_kernel<1><<<dim3(64, DDIM / 128, NEXP), 256, 0, stream>>>(
      hbuf, w2t, nullptr, ybuf, cnt, base, ids);
  combine_kernel<<<NTOK, 256, 0, stream>>>(ybuf, out, epos, base);
}

// Round 4
// 469.546 us; speedup vs baseline: 3.1352x; 1.0081x over previous
//
#include <hip/hip_runtime.h>
#include <hip/hip_bf16.h>
#include <cstdint>

typedef unsigned short u16;
typedef unsigned int u32;
typedef short s16x8 __attribute__((ext_vector_type(8)));
typedef float f32x4 __attribute__((ext_vector_type(4)));

// Problem constants (B=4, T=2048, D=1024, E=8, H=2048, K=2)
constexpr int NTOK = 8192;
constexpr int DDIM = 1024;
constexpr int NEXP = 8;
constexpr int HDIM = 2048;
constexpr int NPAIR = NTOK * 2;   // 16384

// d_out layout (floats), concatenated tuple
constexpr size_t OFF_OUT   = 0;
constexpr size_t OFF_AUX   = 8388608;
constexpr size_t OFF_PROBS = 8388609;
constexpr size_t OFF_TIDX  = 8454145;
constexpr size_t OFF_TPR   = 8470529;

// workspace layout (bytes)
constexpr size_t WS_CNT  = 0;          // 8 int
constexpr size_t WS_PSUM = 32;         // 8 float
constexpr size_t WS_BASE = 64;         // 8 int
constexpr size_t WS_IDS  = 1024;       // 8*8192 int   -> ends 263168
constexpr size_t WS_PRW  = 263168;     // 8*8192 float -> ends 525312
constexpr size_t WS_XB   = 525312;     // 8192*1024 bf16
constexpr size_t WS_W1T  = 17302528;   // 8*2048*1024 bf16 (transposed [E][H][D])
constexpr size_t WS_W2T  = 50856960;   // 8*1024*2048 bf16 (transposed [E][D][H])
constexpr size_t WS_H    = 84411392;   // 16384*2048 bf16
constexpr size_t WS_NEED = 151520256;

__device__ __forceinline__ u16 f2b(float f) {
  u32 u = __float_as_uint(f);
  u32 r = (u + 0x7fffu + ((u >> 16) & 1u)) >> 16;
  return (u16)r;
}

typedef const uint32_t __attribute__((address_space(1)))* gptr_t;
typedef uint32_t __attribute__((address_space(3)))* lptr_t;

__device__ __forceinline__ void gload16(const void* gp, void* lp) {
  __builtin_amdgcn_global_load_lds((gptr_t)gp, (lptr_t)(uintptr_t)lp, 16, 0, 0);
}

// ------------- transpose + convert: in [E][R][C] f32 -> out [E][C][R] bf16 -------------
__global__ __launch_bounds__(256) void tconv_kernel(const float* __restrict__ in,
                                                    u16* __restrict__ out, int R, int C) {
  __shared__ float tile[64][65];
  int e = blockIdx.z;
  int c0 = blockIdx.x * 64, r0 = blockIdx.y * 64;
  int tx = threadIdx.x & 15, ty = threadIdx.x >> 4;
  const float* src = in + (size_t)e * R * C;
#pragma unroll
  for (int i = 0; i < 4; ++i) {
    int r = ty + i * 16;
    float4 v = *(const float4*)(src + (size_t)(r0 + r) * C + c0 + tx * 4);
    tile[r][tx * 4 + 0] = v.x; tile[r][tx * 4 + 1] = v.y;
    tile[r][tx * 4 + 2] = v.z; tile[r][tx * 4 + 3] = v.w;
  }
  __syncthreads();
  u16* dst = out + (size_t)e * R * C;
#pragma unroll
  for (int i = 0; i < 4; ++i) {
    int c = ty + i * 16;
    ushort4 o;
    o.x = f2b(tile[tx * 4 + 0][c]); o.y = f2b(tile[tx * 4 + 1][c]);
    o.z = f2b(tile[tx * 4 + 2][c]); o.w = f2b(tile[tx * 4 + 3][c]);
    *(ushort4*)(dst + (size_t)(c0 + c) * R + r0 + tx * 4) = o;
  }
}

// ---------------- router: 64 tokens/block; fused x->bf16; block-local counting ----------------
__global__ __launch_bounds__(256) void router_kernel(
    const float* __restrict__ x, const float* __restrict__ gw,
    u16* __restrict__ xb, float* __restrict__ outbuf,
    int* __restrict__ cnt, float* __restrict__ psum,
    int* __restrict__ ids, float* __restrict__ prw) {
  __shared__ float gwl[DDIM * NEXP];  // 32 KB
  __shared__ int lcnt[NEXP];
  __shared__ float psl[NEXP];
  __shared__ int gbl[NEXP];

  const int tid = threadIdx.x;
#pragma unroll
  for (int k = 0; k < 8; ++k)
    ((float4*)gwl)[tid + k * 256] = ((const float4*)gw)[tid + k * 256];
  if (tid < NEXP) { lcnt[tid] = 0; psl[tid] = 0.f; }
  __syncthreads();

  const int tloc = tid >> 2, part = tid & 3;
  const int t = blockIdx.x * 64 + tloc;
  double acc[NEXP];
#pragma unroll
  for (int e = 0; e < NEXP; ++e) acc[e] = 0.0;

  const float* xrow = x + (size_t)t * DDIM + part * 256;
  u16* xbrow = xb + (size_t)t * DDIM + part * 256;
  for (int i = 0; i < 64; ++i) {
    float4 v = ((const float4*)xrow)[i];
    ushort4 o;
    o.x = f2b(v.x); o.y = f2b(v.y); o.z = f2b(v.z); o.w = f2b(v.w);
    ((ushort4*)xbrow)[i] = o;
    const float* g = &gwl[(part * 256 + i * 4) * NEXP];
#pragma unroll
    for (int j = 0; j < 4; ++j) {
      double xs = (double)((const float*)&v)[j];
#pragma unroll
      for (int e = 0; e < NEXP; ++e) acc[e] += xs * (double)g[j * NEXP + e];
    }
  }
  // parts of one token sit on 4 consecutive lanes -> butterfly reduce
#pragma unroll
  for (int e = 0; e < NEXP; ++e) {
    acc[e] += __shfl_xor(acc[e], 1);
    acc[e] += __shfl_xor(acc[e], 2);
  }

  int e0 = 0, e1 = 0, lp0 = 0, lp1 = 0;
  float tp0 = 0.f, tp1 = 0.f;
  if (part == 0) {
    float l[NEXP];
#pragma unroll
    for (int e = 0; e < NEXP; ++e) l[e] = (float)acc[e];
    float m = l[0];
#pragma unroll
    for (int e = 1; e < NEXP; ++e) m = fmaxf(m, l[e]);
    float p[NEXP], s = 0.f;
#pragma unroll
    for (int e = 0; e < NEXP; ++e) { p[e] = expf(l[e] - m); s += p[e]; }
    float inv = 1.0f / s;
#pragma unroll
    for (int e = 0; e < NEXP; ++e) {
      p[e] *= inv;
      outbuf[OFF_PROBS + (size_t)t * NEXP + e] = p[e];
      atomicAdd(&psl[e], p[e]);
    }
#pragma unroll
    for (int e = 1; e < NEXP; ++e) if (p[e] > p[e0]) e0 = e;
    e1 = -1;
#pragma unroll
    for (int e = 0; e < NEXP; ++e)
      if (e != e0 && (e1 < 0 || p[e] > p[e1])) e1 = e;
    float ps = p[e0] + p[e1];
    tp0 = p[e0] / ps;
    tp1 = p[e1] / ps;
    outbuf[OFF_TIDX + t * 2 + 0] = (float)e0;
    outbuf[OFF_TIDX + t * 2 + 1] = (float)e1;
    outbuf[OFF_TPR + t * 2 + 0] = tp0;
    outbuf[OFF_TPR + t * 2 + 1] = tp1;
    lp0 = atomicAdd(&lcnt[e0], 1);
    lp1 = atomicAdd(&lcnt[e1], 1);
  }
  __syncthreads();
  if (tid < NEXP) {
    gbl[tid] = atomicAdd(&cnt[tid], lcnt[tid]);
    atomicAdd(&psum[tid], psl[tid]);
  }
  __syncthreads();
  if (part == 0) {
    int pos0 = gbl[e0] + lp0;
    int pos1 = gbl[e1] + lp1;
    ids[e0 * NTOK + pos0] = t;
    ids[e1 * NTOK + pos1] = t;
    prw[e0 * NTOK + pos0] = tp0;
    prw[e1 * NTOK + pos1] = tp1;
  }
}

// ---------------- bases + aux loss ----------------
__global__ void finalize_kernel(const int* __restrict__ cnt,
                                const float* __restrict__ psum,
                                int* __restrict__ base, float* __restrict__ outbuf) {
  if (threadIdx.x == 0 && blockIdx.x == 0) {
    int b = 0;
    float aux = 0.f;
    for (int e = 0; e < NEXP; ++e) {
      base[e] = b;
      b += cnt[e];
      aux += (float)cnt[e] * psum[e];
    }
    outbuf[OFF_AUX] = aux * (float)NEXP / ((float)NTOK * (float)NTOK);
  }
}

// ---------------- grouped GEMM, double-buffered prefetch 2-phase ----------------
// MODE 0: A = x_bf16 gathered rows [*,1024], B = w1t [E][2048][1024], C = h (bf16, gelu)
// MODE 1: A = h contiguous rows   [*,2048], B = w2t [E][1024][2048],
//         epilogue: out[tok] += prob * v (fused combine, atomic f32)
template <int MODE>
__global__ __launch_bounds__(256) void moe_gemm_kernel(
    const u16* __restrict__ Asrc, const u16* __restrict__ Bt,
    u16* __restrict__ hout, float* __restrict__ yout,
    const int* __restrict__ cnt, const int* __restrict__ base,
    const int* __restrict__ ids, const float* __restrict__ prw) {
  constexpr int KDIM = (MODE == 0) ? 1024 : 2048;
  constexpr int NDIM = (MODE == 0) ? 2048 : 1024;
  constexpr int NT = KDIM / 64;
  const int e = blockIdx.z;
  const int cnte = cnt[e];
  const int m0 = blockIdx.x * 128;
  if (m0 >= cnte) return;
  const int n0 = blockIdx.y * 128;
  const int gbase = base[e];

  __shared__ u16 Al[2][128 * 64];
  __shared__ u16 Bl[2][128 * 64];

  const int tid = threadIdx.x;
  const int lane = tid & 63, wid = tid >> 6;
  const int wm = (wid >> 1) * 64, wn = (wid & 1) * 64;
  const int r15 = lane & 15, l4 = lane >> 4;

  // staging precompute: per q, LDS slot j=q*256+tid -> row=j>>3, chunk cp=j&7,
  // holds global chunk c = cp ^ (row&7)  (both-sides XOR swizzle)
  const char* aptr[4];
  const char* bptr[4];
#pragma unroll
  for (int q = 0; q < 4; ++q) {
    int j = q * 256 + tid;
    int row = j >> 3;
    int c = (j & 7) ^ (row & 7);
    size_t rowoff;
    if (MODE == 0) {
      int mm = m0 + row;
      int tok = (mm < cnte) ? ids[e * NTOK + mm] : 0;
      rowoff = (size_t)tok * KDIM;
    } else {
      int gr = gbase + m0 + row;
      if (gr > NPAIR - 1) gr = NPAIR - 1;
      rowoff = (size_t)gr * KDIM;
    }
    aptr[q] = (const char*)Asrc + (rowoff + (size_t)c * 8) * 2;
    size_t nrow = (size_t)e * NDIM + n0 + row;
    bptr[q] = (const char*)Bt + (nrow * KDIM + (size_t)c * 8) * 2;
  }

  f32x4 acc[4][4];
#pragma unroll
  for (int i = 0; i < 4; ++i)
#pragma unroll
    for (int jn = 0; jn < 4; ++jn) acc[i][jn] = (f32x4){0.f, 0.f, 0.f, 0.f};

  // prologue: stage tile 0 into buffer 0
#pragma unroll
  for (int q = 0; q < 4; ++q) {
    gload16(aptr[q], (void*)&Al[0][(size_t)(q * 256 + tid) * 8]);
    gload16(bptr[q], (void*)&Bl[0][(size_t)(q * 256 + tid) * 8]);
  }
  asm volatile("s_waitcnt vmcnt(0)" ::: "memory");
  __syncthreads();

  int cur = 0;
  for (int kt = 0; kt < NT; ++kt) {
    // issue next-tile loads into the other buffer BEFORE computing this one
    if (kt + 1 < NT) {
      const size_t kofs = (size_t)(kt + 1) * 128;  // bytes: 64 bf16
#pragma unroll
      for (int q = 0; q < 4; ++q) {
        gload16(aptr[q] + kofs, (void*)&Al[cur ^ 1][(size_t)(q * 256 + tid) * 8]);
        gload16(bptr[q] + kofs, (void*)&Bl[cur ^ 1][(size_t)(q * 256 + tid) * 8]);
      }
    }
    const s16x8* Av = (const s16x8*)Al[cur];
    const s16x8* Bv = (const s16x8*)Bl[cur];
#pragma unroll
    for (int kh = 0; kh < 2; ++kh) {
      s16x8 af[4], bfr[4];
#pragma unroll
      for (int mi = 0; mi < 4; ++mi) {
        int row = wm + mi * 16 + r15;
        af[mi] = Av[row * 8 + ((kh * 4 + l4) ^ (row & 7))];
      }
#pragma unroll
      for (int ni = 0; ni < 4; ++ni) {
        int row = wn + ni * 16 + r15;
        bfr[ni] = Bv[row * 8 + ((kh * 4 + l4) ^ (row & 7))];
      }
#pragma unroll
      for (int mi = 0; mi < 4; ++mi)
#pragma unroll
        for (int ni = 0; ni < 4; ++ni)
          acc[mi][ni] = __builtin_amdgcn_mfma_f32_16x16x32_bf16(
              af[mi], bfr[ni], acc[mi][ni], 0, 0, 0);
    }
    // barrier drains vmcnt(0)+lgkmcnt(0): next tile landed, all reads of cur done
    __syncthreads();
    cur ^= 1;
  }

  // epilogue: C/D layout col = lane&15, row = (lane>>4)*4 + j
#pragma unroll
  for (int mi = 0; mi < 4; ++mi) {
#pragma unroll
    for (int jr = 0; jr < 4; ++jr) {
      int rl = wm + mi * 16 + l4 * 4 + jr;
      if (m0 + rl < cnte) {
        if (MODE == 0) {
          size_t grow = (size_t)(gbase + m0 + rl);
#pragma unroll
          for (int ni = 0; ni < 4; ++ni) {
            float v = acc[mi][ni][jr];
            v = 0.5f * v * (1.0f + erff(v * 0.70710678118654752f));
            int col = n0 + wn + ni * 16 + r15;
            hout[grow * NDIM + col] = f2b(v);
          }
        } else {
          int tok = ids[e * NTOK + m0 + rl];
          float p = prw[e * NTOK + m0 + rl];
#pragma unroll
          for (int ni = 0; ni < 4; ++ni) {
            int col = n0 + wn + ni * 16 + r15;
            atomicAdd(&yout[(size_t)tok * DDIM + col], p * acc[mi][ni][jr]);
          }
        }
      }
    }
  }
}

extern "C" void kernel_launch(void* const* d_in, const int* in_sizes, int n_in,
                              void* d_out, int out_size, void* d_ws, size_t ws_size,
                              hipStream_t stream) {
  const float* x = (const float*)d_in[0];
  const float* gw = (const float*)d_in[1];
  const float* w1 = (const float*)d_in[2];
  const float* w2 = (const float*)d_in[3];
  float* out = (float*)d_out;
  char* w = (char*)d_ws;
  if (ws_size < WS_NEED) return;  // insufficient workspace -> loud failure

  int* cnt = (int*)(w + WS_CNT);
  float* psum = (float*)(w + WS_PSUM);
  int* base = (int*)(w + WS_BASE);
  int* ids = (int*)(w + WS_IDS);
  float* prw = (float*)(w + WS_PRW);
  u16* xb = (u16*)(w + WS_XB);
  u16* w1t = (u16*)(w + WS_W1T);
  u16* w2t = (u16*)(w + WS_W2T);
  u16* hbuf = (u16*)(w + WS_H);

  (void)hipMemsetAsync(w, 0, 96, stream);
  (void)hipMemsetAsync(out + OFF_OUT, 0, (size_t)NTOK * DDIM * sizeof(float), stream);
  // router also emits xb (x converted to bf16) and per-(e,pos) gate probs
  router_kernel<<<NTOK / 64, 256, 0, stream>>>(x, gw, xb, out, cnt, psum, ids, prw);
  // w1 [E][1024][2048] -> w1t [E][2048][1024]
  tconv_kernel<<<dim3(HDIM / 64, DDIM / 64, NEXP), 256, 0, stream>>>(w1, w1t, DDIM, HDIM);
  // w2 [E][2048][1024] -> w2t [E][1024][2048]
  tconv_kernel<<<dim3(DDIM / 64, HDIM / 64, NEXP), 256, 0, stream>>>(w2, w2t, HDIM, DDIM);
  finalize_kernel<<<1, 64, 0, stream>>>(cnt, psum, base, out);
  moe_gemm_kernel<0><<<dim3(64, HDIM / 128, NEXP), 256, 0, stream>>>(
      xb, w1t, hbuf, nullptr, cnt, base, ids, prw);
  moe_gemm_kernel<1><<<dim3(64, DDIM / 128, NEXP), 256, 0, stream>>>(
      hbuf, w2t, nullptr, out + OFF_OUT, cnt, base, ids, prw);
}